// Round 1
// baseline (442.099 us; speedup 1.0000x reference)
//
#include <hip/hip_runtime.h>

// Bilinear per-image shift with mirror boundary — uniform-shift formulation.
//
// dx,dy constant per image, x,y integer =>
//   floor(x - dx) = x + floor(-dx),  frac(x - dx) = frac(-dx)
// so the op is a per-image constant integer shift + constant 4-tap blend.
//
// R4 (this round):
//  - 9th tap via __shfl_down from the right-neighbor lane's first tap
//    (columns are wave-contiguous; neighbor's u[0] == R0[mirror(xs+8)] in
//    ALL cases — interior or mirrored — which is exactly the reference's
//    x1m tap). Removes 2 scalar dword loads/thread: read VMEM 6 -> 4 ops.
//  - Nontemporal float4 stores: output is write-once/never-re-read; keep
//    it from thrashing L2 so the R0/R1 input-row reuse window stays hot.
//
// Traffic floor: ~256 MB fetch + 256 MB write -> ~81 us @ 6.3 TB/s.
// Kernel slice est. ~107 us of the 433 us bench (2x ~163 us poison fills
// are harness-side); target ~88-95 us.

// float4 with 4-byte alignment: lets the compiler emit global_load_dwordx4
// at dword-aligned (not 16B-aligned) addresses.
typedef float f4u __attribute__((ext_vector_type(4), aligned(4)));
// naturally-aligned float4 for the (32B-aligned) output stores
typedef float f4a __attribute__((ext_vector_type(4)));

__device__ __forceinline__ int mirror_small(int v) {
    // Reflect into [0,511]; valid for v in [-1022, 1533].
    v = abs(v);
    return (v > 511) ? (1022 - v) : v;
}

__global__ __launch_bounds__(256) void shift_bilinear_kernel(
    const float* __restrict__ img,
    const float* __restrict__ dxdy,
    float* __restrict__ out)
{
    constexpr int W = 512, H = 512;

    // 2048 px per block (4 rows), 128 blocks per image -> image index is
    // blockIdx-derived => dxdy load is wave-uniform.
    const int b  = blockIdx.x >> 7;
    const int lp = ((blockIdx.x & 127) << 11) + ((int)threadIdx.x << 3);
    const int y  = lp >> 9;           // local row (one wave == one row)
    const int x8 = lp & (W - 1);      // 8-px segment start (multiple of 8)

    const float dy = dxdy[2 * b];
    const float dx = dxdy[2 * b + 1];

    // Per-image constants (uniform across the block).
    const float ny  = -dy,        nx  = -dx;
    const float ayf = floorf(ny), axf = floorf(nx);
    const float fy  = ny - ayf,   fx  = nx - axf;
    const int   ia  = (int)ayf,   ja  = (int)axf;

    const float gy = 1.0f - fy, gx = 1.0f - fx;
    const float w00 = gy * gx, w01 = gy * fx, w10 = fy * gx, w11 = fy * fx;

    // Source rows (mirror).
    const int r0 = mirror_small(y + ia);
    const int r1 = mirror_small(y + ia + 1);
    const float* __restrict__ R0 = img + (b * H + r0) * W;
    const float* __restrict__ R1 = img + (b * H + r1) * W;

    const int xs = x8 + ja;           // source column of first tap

    float u[8], v[8];                 // taps xs..xs+7 from the two rows
    if (xs >= 0 && xs <= W - 8) {
        // Fast path: unaligned vector loads (dword-aligned is enough).
        const f4u ua = *(const f4u*)(R0 + xs);
        const f4u ub = *(const f4u*)(R0 + xs + 4);
        const f4u va = *(const f4u*)(R1 + xs);
        const f4u vb = *(const f4u*)(R1 + xs + 4);
        u[0]=ua.x; u[1]=ua.y; u[2]=ua.z; u[3]=ua.w;
        u[4]=ub.x; u[5]=ub.y; u[6]=ub.z; u[7]=ub.w;
        v[0]=va.x; v[1]=va.y; v[2]=va.z; v[3]=va.w;
        v[4]=vb.x; v[5]=vb.y; v[6]=vb.z; v[7]=vb.w;
    } else {
        // Border segments (typically one lane per wave): mirrored gathers.
#pragma unroll
        for (int k = 0; k < 8; ++k) {
            const int c = mirror_small(xs + k);
            u[k] = R0[c];
            v[k] = R1[c];
        }
    }

    // 9th tap: right-neighbor lane's first tap. Correct in all cases:
    //  - neighbor interior:  u[0] = R0[xs+8]
    //  - neighbor mirrored:  u[0] = R0[mirror(xs+8)]  (== reference x1m tap)
    // Lane 63 has no right neighbor in this row -> scalar mirrored load.
    float u8 = __shfl_down(u[0], 1);
    float v8 = __shfl_down(v[0], 1);
    if ((threadIdx.x & 63) == 63) {
        const int c = mirror_small(xs + 8);
        u8 = R0[c];
        v8 = R1[c];
    }

    f4a lo, hi;
    lo.x = w00*u[0] + w01*u[1] + w10*v[0] + w11*v[1];
    lo.y = w00*u[1] + w01*u[2] + w10*v[1] + w11*v[2];
    lo.z = w00*u[2] + w01*u[3] + w10*v[2] + w11*v[3];
    lo.w = w00*u[3] + w01*u[4] + w10*v[3] + w11*v[4];
    hi.x = w00*u[4] + w01*u[5] + w10*v[4] + w11*v[5];
    hi.y = w00*u[5] + w01*u[6] + w10*v[5] + w11*v[6];
    hi.z = w00*u[6] + w01*u[7] + w10*v[6] + w11*v[7];
    hi.w = w00*u[7] + w01*u8   + w10*v[7] + w11*v8;

    // Output: write-once stream -> nontemporal, keep L2 for input rows.
    float* o = out + ((size_t)b << 18) + lp;
    __builtin_nontemporal_store(lo, (f4a*)(o));
    __builtin_nontemporal_store(hi, (f4a*)(o + 4));
}

extern "C" void kernel_launch(void* const* d_in, const int* in_sizes, int n_in,
                              void* d_out, int out_size, void* d_ws, size_t ws_size,
                              hipStream_t stream) {
    const float* images = (const float*)d_in[0];
    const float* dxdy   = (const float*)d_in[1];
    float*       out    = (float*)d_out;

    // out_size = 256*512*512 px; 2048 px per block.
    const int blocks = out_size >> 11;
    shift_bilinear_kernel<<<blocks, 256, 0, stream>>>(images, dxdy, out);
}

// Round 2
// 429.656 us; speedup vs baseline: 1.0290x; 1.0290x over previous
//
#include <hip/hip_runtime.h>

// Bilinear per-image shift with mirror boundary — uniform-shift formulation.
//
// dx,dy constant per image, x,y integer =>
//   floor(x - dx) = x + floor(-dx),  frac(x - dx) = frac(-dx)
// so the op is a per-image constant integer shift + constant 4-tap blend.
//
// R5 (this round):
//  - Row-pair scheme: one wave computes output rows {2p, 2p+1} from THREE
//    source rows (rA, rB, rC). The shared middle row rB is loaded once and
//    reused in registers for both outputs -> read VMEM ops and L1/L2 read
//    traffic drop 25% per output byte (was 2 source rows per output row,
//    now 1.5). HBM fetch unchanged (~256 MB).
//  - Reverted R4's nontemporal stores (suspected +9 us regression: stores
//    are full-line coalesced; NT demotes them to a worse write path).
//  - Kept the shuffle-sourced 9th tap (neighbor lane's first tap is the
//    reference's x1m tap in all cases, incl. mirrored).
//
// Traffic floor: ~256 MB fetch + 256 MB write -> ~81 us @ 6.3 TB/s.
// Kernel slice est. ~112 us of the 442 us bench (2x ~165 us poison fills
// are harness-side); target ~90-95 us.

// float4 with 4-byte alignment: lets the compiler emit global_load_dwordx4
// at dword-aligned (not 16B-aligned) addresses.
typedef float f4u __attribute__((ext_vector_type(4), aligned(4)));

__device__ __forceinline__ int mirror_small(int v) {
    // Reflect into [0,511]; valid for v in [-1022, 1533].
    v = abs(v);
    return (v > 511) ? (1022 - v) : v;
}

__global__ __launch_bounds__(256) void shift_bilinear_kernel(
    const float* __restrict__ img,
    const float* __restrict__ dxdy,
    float* __restrict__ out)
{
    constexpr int W = 512, H = 512;

    // One wave == one row-pair (2 output rows x 512 px, 8 px/lane).
    // 4 waves/block -> 8 output rows per block, 64 blocks per image.
    const int b    = blockIdx.x >> 6;
    const int wave = (int)threadIdx.x >> 6;
    const int lane = (int)threadIdx.x & 63;
    const int p    = ((blockIdx.x & 63) << 2) + wave;   // row pair 0..255
    const int y0   = p << 1;                            // even output row
    const int x8   = lane << 3;                         // 8-px segment start

    const float dy = dxdy[2 * b];
    const float dx = dxdy[2 * b + 1];

    // Per-image constants (uniform across the block).
    const float ny  = -dy,        nx  = -dx;
    const float ayf = floorf(ny), axf = floorf(nx);
    const float fy  = ny - ayf,   fx  = nx - axf;
    const int   ia  = (int)ayf,   ja  = (int)axf;

    const float gy = 1.0f - fy, gx = 1.0f - fx;
    const float w00 = gy * gx, w01 = gy * fx, w10 = fy * gx, w11 = fy * fx;

    // Three source rows (mirror): row y0 blends rA,rB; row y0+1 blends rB,rC.
    const int rA = mirror_small(y0 + ia);
    const int rB = mirror_small(y0 + ia + 1);
    const int rC = mirror_small(y0 + ia + 2);
    const float* __restrict__ RA = img + ((size_t)b * H + rA) * W;
    const float* __restrict__ RB = img + ((size_t)b * H + rB) * W;
    const float* __restrict__ RC = img + ((size_t)b * H + rC) * W;

    const int xs = x8 + ja;           // source column of first tap

    float a[8], m[8], c[8];           // taps xs..xs+7 from the three rows
    if (xs >= 0 && xs <= W - 8) {
        // Fast path: unaligned vector loads (dword-aligned is enough).
        const f4u a0 = *(const f4u*)(RA + xs);
        const f4u a1 = *(const f4u*)(RA + xs + 4);
        const f4u m0 = *(const f4u*)(RB + xs);
        const f4u m1 = *(const f4u*)(RB + xs + 4);
        const f4u c0 = *(const f4u*)(RC + xs);
        const f4u c1 = *(const f4u*)(RC + xs + 4);
        a[0]=a0.x; a[1]=a0.y; a[2]=a0.z; a[3]=a0.w;
        a[4]=a1.x; a[5]=a1.y; a[6]=a1.z; a[7]=a1.w;
        m[0]=m0.x; m[1]=m0.y; m[2]=m0.z; m[3]=m0.w;
        m[4]=m1.x; m[5]=m1.y; m[6]=m1.z; m[7]=m1.w;
        c[0]=c0.x; c[1]=c0.y; c[2]=c0.z; c[3]=c0.w;
        c[4]=c1.x; c[5]=c1.y; c[6]=c1.z; c[7]=c1.w;
    } else {
        // Border segments (one lane per wave, typically): mirrored gathers.
#pragma unroll
        for (int k = 0; k < 8; ++k) {
            const int col = mirror_small(xs + k);
            a[k] = RA[col];
            m[k] = RB[col];
            c[k] = RC[col];
        }
    }

    // 9th tap: right-neighbor lane's first tap. Correct in all cases:
    //  - neighbor interior:  tap = R[xs+8]
    //  - neighbor mirrored:  tap = R[mirror(xs+8)]  (== reference x1m tap)
    // Lane 63 has no right neighbor -> scalar mirrored loads.
    float a8 = __shfl_down(a[0], 1);
    float m8 = __shfl_down(m[0], 1);
    float c8 = __shfl_down(c[0], 1);
    if (lane == 63) {
        const int col = mirror_small(xs + 8);
        a8 = RA[col];
        m8 = RB[col];
        c8 = RC[col];
    }

    // Output row y0: blend rows a (top) and m (bottom).
    float4 lo0, hi0;
    lo0.x = w00*a[0] + w01*a[1] + w10*m[0] + w11*m[1];
    lo0.y = w00*a[1] + w01*a[2] + w10*m[1] + w11*m[2];
    lo0.z = w00*a[2] + w01*a[3] + w10*m[2] + w11*m[3];
    lo0.w = w00*a[3] + w01*a[4] + w10*m[3] + w11*m[4];
    hi0.x = w00*a[4] + w01*a[5] + w10*m[4] + w11*m[5];
    hi0.y = w00*a[5] + w01*a[6] + w10*m[5] + w11*m[6];
    hi0.z = w00*a[6] + w01*a[7] + w10*m[6] + w11*m[7];
    hi0.w = w00*a[7] + w01*a8   + w10*m[7] + w11*m8;

    // Output row y0+1: blend rows m (top) and c (bottom).
    float4 lo1, hi1;
    lo1.x = w00*m[0] + w01*m[1] + w10*c[0] + w11*c[1];
    lo1.y = w00*m[1] + w01*m[2] + w10*c[1] + w11*c[2];
    lo1.z = w00*m[2] + w01*m[3] + w10*c[2] + w11*c[3];
    lo1.w = w00*m[3] + w01*m[4] + w10*c[3] + w11*c[4];
    hi1.x = w00*m[4] + w01*m[5] + w10*c[4] + w11*c[5];
    hi1.y = w00*m[5] + w01*m[6] + w10*c[5] + w11*c[6];
    hi1.z = w00*m[6] + w01*m[7] + w10*c[6] + w11*c[7];
    hi1.w = w00*m[7] + w01*m8   + w10*c[7] + w11*c8;

    float* o0 = out + ((size_t)b << 18) + ((size_t)y0 << 9) + x8;
    float* o1 = o0 + W;
    *(float4*)(o0)     = lo0;
    *(float4*)(o0 + 4) = hi0;
    *(float4*)(o1)     = lo1;
    *(float4*)(o1 + 4) = hi1;
}

extern "C" void kernel_launch(void* const* d_in, const int* in_sizes, int n_in,
                              void* d_out, int out_size, void* d_ws, size_t ws_size,
                              hipStream_t stream) {
    const float* images = (const float*)d_in[0];
    const float* dxdy   = (const float*)d_in[1];
    float*       out    = (float*)d_out;

    // out_size = 256*512*512 px; 4096 px (8 rows) per block.
    const int blocks = out_size >> 12;
    shift_bilinear_kernel<<<blocks, 256, 0, stream>>>(images, dxdy, out);
}